// Round 1
// baseline (336.117 us; speedup 1.0000x reference)
//
#include <hip/hip_runtime.h>
#include <math.h>

// Problem constants (B=16, C=3, H=W=512)
#define PAD 3
constexpr int W = 512;
constexpr int HIMG = 512;
constexpr int L = W * HIMG;              // 262144 = 2^18 elements per row
constexpr int LOG2L = 18;
constexpr int TILE = 2048;
constexpr int TPB = 256;
constexpr int EPT = TILE / TPB;          // 8 elements per thread
constexpr int TILES_PER_ROW = L / TILE;  // 128

__device__ __forceinline__ float softplusf(float v) {
    // logaddexp(0, v) = max(v,0) + log1p(exp(-|v|))
    return fmaxf(v, 0.0f) + log1pf(expf(-fabsf(v)));
}

// ---------------- Pass 1: horizontal 7-wide OR (reflect) ----------------
__global__ void dilate_h_kernel(const float* __restrict__ t,
                                unsigned char* __restrict__ augH, int ntot) {
    int g = blockIdx.x * blockDim.x + threadIdx.x;
    if (g >= ntot) return;
    int j = g & (W - 1);
    int rowbase = g - j;
    bool m = false;
#pragma unroll
    for (int d = -PAD; d <= PAD; ++d) {
        int jj = j + d;
        jj = jj < 0 ? -jj : (jj >= W ? 2 * W - 2 - jj : jj);
        m = m || (t[rowbase + jj] > 0.0f);
    }
    augH[g] = (unsigned char)m;
}

// ---------------- Pass 2: vertical 7-tall OR (reflect) ----------------
__global__ void dilate_v_kernel(const unsigned char* __restrict__ augH,
                                unsigned char* __restrict__ aug, int ntot) {
    int g = blockIdx.x * blockDim.x + threadIdx.x;
    if (g >= ntot) return;
    int l = g & (L - 1);
    int imgbase = g - l;
    int i = l >> 9;          // / W
    int j = l & (W - 1);
    bool m = false;
#pragma unroll
    for (int d = -PAD; d <= PAD; ++d) {
        int ii = i + d;
        ii = ii < 0 ? -ii : (ii >= HIMG ? 2 * HIMG - 2 - ii : ii);
        m = m || (augH[imgbase + ii * W + j] != 0);
    }
    aug[g] = (unsigned char)m;
}

// ---------------- Pass 3: per-tile counts (pos / false-pos / neg) ----------------
__global__ void count_tiles_kernel(const float* __restrict__ x, const float* __restrict__ t,
                                   const unsigned char* __restrict__ aug,
                                   int* __restrict__ cPos, int* __restrict__ cFp,
                                   int* __restrict__ cNeg) {
    int tile = blockIdx.x;
    int tid = threadIdx.x;
    int base = tile * TILE + tid * EPT;
    int p = 0, f = 0, n = 0;
#pragma unroll
    for (int e = 0; e < EPT; ++e) {
        int g = base + e;
        float tv = t[g];
        float xv = x[g];
        bool notAug = (aug[g] == 0);
        p += (tv > 0.0f) ? 1 : 0;
        n += notAug ? 1 : 0;
        f += (notAug && xv > 0.0f) ? 1 : 0;
    }
    __shared__ int sp[TPB], sf[TPB], sn[TPB];
    sp[tid] = p; sf[tid] = f; sn[tid] = n;
    __syncthreads();
    for (int off = TPB / 2; off > 0; off >>= 1) {
        if (tid < off) { sp[tid] += sp[tid + off]; sf[tid] += sf[tid + off]; sn[tid] += sn[tid + off]; }
        __syncthreads();
    }
    if (tid == 0) { cPos[tile] = sp[0]; cFp[tile] = sf[0]; cNeg[tile] = sn[0]; }
}

// ---------------- Pass 4: per-row exclusive scan of tile counts ----------------
__global__ void scan_rows_kernel(const int* __restrict__ cPos, const int* __restrict__ cFp,
                                 const int* __restrict__ cNeg,
                                 int* __restrict__ oPos, int* __restrict__ oFp,
                                 int* __restrict__ oNeg,
                                 int* __restrict__ rowPos, int* __restrict__ rowFp,
                                 int* __restrict__ rowNeg) {
    int r = blockIdx.x;
    int tid = threadIdx.x;  // blockDim == TILES_PER_ROW
    __shared__ int s[TILES_PER_ROW];
    const int* cs[3] = {cPos, cFp, cNeg};
    int* os[3] = {oPos, oFp, oNeg};
    int* rs[3] = {rowPos, rowFp, rowNeg};
    for (int a = 0; a < 3; ++a) {
        int v = cs[a][r * TILES_PER_ROW + tid];
        s[tid] = v;
        __syncthreads();
        for (int off = 1; off < TILES_PER_ROW; off <<= 1) {
            int add = (tid >= off) ? s[tid - off] : 0;
            __syncthreads();
            s[tid] += add;
            __syncthreads();
        }
        int incl = s[tid];
        os[a][r * TILES_PER_ROW + tid] = incl - v;
        if (tid == TILES_PER_ROW - 1) rs[a][r] = incl;
        __syncthreads();
    }
}

// ---------------- Pass 5: stable scatter-compaction of xp (pos) and xf (chosen) --------
__global__ void scatter_kernel(const float* __restrict__ x, const float* __restrict__ t,
                               const unsigned char* __restrict__ aug,
                               const int* __restrict__ oPos, const int* __restrict__ oFp,
                               const int* __restrict__ oNeg, const int* __restrict__ rowFp,
                               float* __restrict__ xp, float* __restrict__ xf) {
    int tile = blockIdx.x;
    int tid = threadIdx.x;
    int r = tile / TILES_PER_ROW;
    bool useFp = rowFp[r] > 0;
    int base = tile * TILE + tid * EPT;

    float xv[EPT];
    bool isPos[EPT], isCh[EPT];
    int p = 0, c = 0;
#pragma unroll
    for (int e = 0; e < EPT; ++e) {
        int g = base + e;
        xv[e] = x[g];
        float tv = t[g];
        bool notAug = (aug[g] == 0);
        isPos[e] = (tv > 0.0f);
        isCh[e] = useFp ? (notAug && xv[e] > 0.0f) : notAug;
        p += isPos[e] ? 1 : 0;
        c += isCh[e] ? 1 : 0;
    }
    // packed block exclusive scan (p in low 16, c in high 16; both <= 2048)
    __shared__ int s[TPB];
    int v = p | (c << 16);
    s[tid] = v;
    __syncthreads();
    for (int off = 1; off < TPB; off <<= 1) {
        int add = (tid >= off) ? s[tid - off] : 0;
        __syncthreads();
        s[tid] += add;
        __syncthreads();
    }
    int excl = s[tid] - v;
    int ep = excl & 0xFFFF;
    int ec = excl >> 16;

    int rL = r * L;
    int pw = rL + oPos[tile] + ep;
    int cw = rL + (useFp ? oFp[tile] : oNeg[tile]) + ec;
#pragma unroll
    for (int e = 0; e < EPT; ++e) {
        if (isPos[e]) xp[pw++] = xv[e];
        if (isCh[e]) xf[cw++] = xv[e];
    }
}

// ---------------- Pass 6: streaming loss reduction ----------------
__global__ void loss_kernel(const float* __restrict__ x, const float* __restrict__ t,
                            const float* __restrict__ xp, const float* __restrict__ xf,
                            const int* __restrict__ rowPos, const int* __restrict__ rowFp,
                            const int* __restrict__ rowNeg,
                            double* __restrict__ acc, int ntot) {
    int tid = threadIdx.x;
    int stride = gridDim.x * blockDim.x;
    double local = 0.0;
    for (int g = blockIdx.x * blockDim.x + tid; g < ntot; g += stride) {
        int r = g >> LOG2L;
        int l = g & (L - 1);
        float xv = x[g];
        float tv = t[g];
        int cp = rowPos[r];
        float dp = (cp > 0) ? xp[r * L + (l % (unsigned)cp)] : 5.0f;
        int cf = rowFp[r];
        int cc = (cf > 0) ? cf : rowNeg[r];
        float df = (cc > 0) ? xf[r * L + (l % (unsigned)cc)] : -5.0f;
        float sim = dp * xv;
        float e = softplusf(sim) - sim * tv        // BCE(sim, t)
                + softplusf(dp) - dp               // BCE(dup_pos, 1)
                + 0.1f * softplusf(dp * df);       // 0.1 * BCE(aug_sim, 0)
        local += (double)e;
    }
    __shared__ double sd[TPB];
    sd[tid] = local;
    __syncthreads();
    for (int off = TPB / 2; off > 0; off >>= 1) {
        if (tid < off) sd[tid] += sd[tid + off];
        __syncthreads();
    }
    if (tid == 0) atomicAdd(acc, sd[0]);
}

__global__ void finalize_kernel(const double* __restrict__ acc, float* __restrict__ out, int ntot) {
    out[0] = (float)(acc[0] / (double)ntot);
}

extern "C" void kernel_launch(void* const* d_in, const int* in_sizes, int n_in,
                              void* d_out, int out_size, void* d_ws, size_t ws_size,
                              hipStream_t stream) {
    const float* x = (const float*)d_in[0];   // input
    const float* t = (const float*)d_in[1];   // target
    float* out = (float*)d_out;

    int ntot = in_sizes[0];                   // 12,582,912
    int R = ntot >> LOG2L;                    // 48 rows
    int numTiles = ntot / TILE;               // 6144

    // Workspace layout
    char* ws = (char*)d_ws;
    size_t off = 0;
    auto alloc = [&](size_t bytes) {
        size_t p = off;
        off = (off + bytes + 255) & ~(size_t)255;
        return (void*)(ws + p);
    };
    double* acc = (double*)alloc(sizeof(double));
    int* cPos = (int*)alloc(numTiles * sizeof(int));
    int* cFp  = (int*)alloc(numTiles * sizeof(int));
    int* cNeg = (int*)alloc(numTiles * sizeof(int));
    int* oPos = (int*)alloc(numTiles * sizeof(int));
    int* oFp  = (int*)alloc(numTiles * sizeof(int));
    int* oNeg = (int*)alloc(numTiles * sizeof(int));
    int* rowPos = (int*)alloc(R * sizeof(int));
    int* rowFp  = (int*)alloc(R * sizeof(int));
    int* rowNeg = (int*)alloc(R * sizeof(int));
    unsigned char* augH = (unsigned char*)alloc((size_t)ntot);
    unsigned char* aug  = (unsigned char*)alloc((size_t)ntot);
    float* xp = (float*)alloc((size_t)ntot * sizeof(float));
    float* xf = (float*)alloc((size_t)ntot * sizeof(float));

    hipMemsetAsync(acc, 0, sizeof(double), stream);

    int nBlocksElem = (ntot + TPB - 1) / TPB;
    dilate_h_kernel<<<nBlocksElem, TPB, 0, stream>>>(t, augH, ntot);
    dilate_v_kernel<<<nBlocksElem, TPB, 0, stream>>>(augH, aug, ntot);
    count_tiles_kernel<<<numTiles, TPB, 0, stream>>>(x, t, aug, cPos, cFp, cNeg);
    scan_rows_kernel<<<R, TILES_PER_ROW, 0, stream>>>(cPos, cFp, cNeg, oPos, oFp, oNeg,
                                                      rowPos, rowFp, rowNeg);
    scatter_kernel<<<numTiles, TPB, 0, stream>>>(x, t, aug, oPos, oFp, oNeg, rowFp, xp, xf);
    loss_kernel<<<4096, TPB, 0, stream>>>(x, t, xp, xf, rowPos, rowFp, rowNeg, acc, ntot);
    finalize_kernel<<<1, 1, 0, stream>>>(acc, out, ntot);
}

// Round 3
// 194.236 us; speedup vs baseline: 1.7305x; 1.7305x over previous
//
#include <hip/hip_runtime.h>
#include <math.h>

// Problem constants (B=16, C=3, H=W=512) -> 48 "rows" of L = 262144 elements.
constexpr int W = 512;
constexpr int HIMG = 512;
constexpr int L = 1 << 18;               // elements per row
constexpr int LOG2L = 18;
constexpr int TPB = 256;
constexpr int TILE = 2048;               // elements per scatter tile
constexpr int TILES_PER_ROW = L / TILE;  // 128
constexpr int WORDS_PER_ROW = L / 64;    // 4096 (64-bit mask words per row)
constexpr int WORDS_PER_TILE = TILE / 64; // 32

typedef unsigned long long ull;

// softplus via native v_exp_f32 / v_log_f32 (abs err ~1e-6; final threshold 3.6e-2)
// __builtin_amdgcn_exp2f(x) = 2^x ; __builtin_amdgcn_logf(x) = log2(x)
__device__ __forceinline__ float softplus_f(float v) {
    return fmaxf(v, 0.0f) +
           0.6931471805599453f *
               __builtin_amdgcn_logf(1.0f + __builtin_amdgcn_exp2f(-fabsf(v) * 1.4426950408889634f));
}

// ---------------- Pass A: build t>0 and x>0 bitmasks via wave ballots ----------------
// Each wave iteration handles 4 words = 256 consecutive elements (coalesced dword loads).
__global__ void mask_kernel(const float* __restrict__ x, const float* __restrict__ t,
                            ull* __restrict__ maskT, ull* __restrict__ maskX, int nwords4) {
    int lane = threadIdx.x & 63;
    int waveId = (blockIdx.x * blockDim.x + threadIdx.x) >> 6;
    int nWaves = (gridDim.x * blockDim.x) >> 6;
    for (int wi = waveId; wi < nwords4; wi += nWaves) {
        int eb = wi * 256;
        int w0 = wi * 4;
        ull bt0 = __ballot(t[eb + lane] > 0.0f);
        ull bt1 = __ballot(t[eb + 64 + lane] > 0.0f);
        ull bt2 = __ballot(t[eb + 128 + lane] > 0.0f);
        ull bt3 = __ballot(t[eb + 192 + lane] > 0.0f);
        ull bx0 = __ballot(x[eb + lane] > 0.0f);
        ull bx1 = __ballot(x[eb + 64 + lane] > 0.0f);
        ull bx2 = __ballot(x[eb + 128 + lane] > 0.0f);
        ull bx3 = __ballot(x[eb + 192 + lane] > 0.0f);
        if (lane < 4) {
            ull v = (lane == 0) ? bt0 : (lane == 1) ? bt1 : (lane == 2) ? bt2 : bt3;
            maskT[w0 + lane] = v;
        } else if (lane < 8) {
            int k = lane - 4;
            ull v = (k == 0) ? bx0 : (k == 1) ? bx1 : (k == 2) ? bx2 : bx3;
            maskX[w0 + k] = v;
        }
    }
}

// ---------------- Pass B1: horizontal 7-wide OR on bit words (reflect) ----------------
__device__ __forceinline__ ull hdil7(ull prev, ull cur, ull next) {
    ull r = cur;
    r |= (cur >> 1) | (next << 63);
    r |= (cur >> 2) | (next << 62);
    r |= (cur >> 3) | (next << 61);
    r |= (cur << 1) | (prev >> 63);
    r |= (cur << 2) | (prev >> 62);
    r |= (cur << 3) | (prev >> 61);
    return r;
}

__global__ void dilate_h_kernel(const ull* __restrict__ maskT, ull* __restrict__ maskH,
                                int nwords) {
    int w = blockIdx.x * blockDim.x + threadIdx.x;
    if (w >= nwords) return;
    int wcol = w & 7;  // 8 words per 512-wide scanline
    ull cur = maskT[w];
    // virtual neighbors implement reflect padding: col -k -> col k ; col 511+k -> col 511-k
    ull prev = wcol ? maskT[w - 1]
                    : ((((cur >> 1) & 1ull) << 63) | (((cur >> 2) & 1ull) << 62) |
                       (((cur >> 3) & 1ull) << 61));
    ull next = (wcol < 7) ? maskT[w + 1]
                          : (((cur >> 62) & 1ull) | (((cur >> 61) & 1ull) << 1) |
                             (((cur >> 60) & 1ull) << 2));
    maskH[w] = hdil7(prev, cur, next);
}

// ---------------- Pass B2: vertical 7-tall OR (reflect) ----------------
__global__ void dilate_v_kernel(const ull* __restrict__ maskH, ull* __restrict__ maskA,
                                int nwords) {
    int w = blockIdx.x * blockDim.x + threadIdx.x;
    if (w >= nwords) return;
    int wimg = w & (WORDS_PER_ROW - 1);  // word index within one 512x512 image
    int scan = wimg >> 3;                // scanline
    int wcol = wimg & 7;
    int base = w - wimg;
    ull out = 0;
#pragma unroll
    for (int d = -3; d <= 3; ++d) {
        int ii = scan + d;
        ii = ii < 0 ? -ii : (ii > HIMG - 1 ? 2 * (HIMG - 1) - ii : ii);
        out |= maskH[base + ii * 8 + wcol];
    }
    maskA[w] = out;
}

// ---------------- Pass C: per-row tile counts + scan + magic divisors ----------------
// One block (128 threads = one per tile) per row; popcount the bitmasks.
__global__ void count_scan_kernel(const ull* __restrict__ maskT, const ull* __restrict__ maskX,
                                  const ull* __restrict__ maskA,
                                  int* __restrict__ oPos, int* __restrict__ oCh,
                                  int* __restrict__ rCp, int* __restrict__ rCc,
                                  ull* __restrict__ rMp, ull* __restrict__ rMc,
                                  int* __restrict__ rUseFp) {
    int r = blockIdx.x;
    int tid = threadIdx.x;  // 0..127
    int wb = r * WORDS_PER_ROW + tid * WORDS_PER_TILE;
    int p = 0, f = 0, n = 0;
#pragma unroll 4
    for (int k = 0; k < WORDS_PER_TILE; ++k) {
        ull wt = maskT[wb + k], wx = maskX[wb + k], wa = maskA[wb + k];
        p += __popcll(wt);
        f += __popcll(wx & ~wa);
        n += __popcll(~wa);
    }
    __shared__ int ssp[TILES_PER_ROW], ssf[TILES_PER_ROW], ssn[TILES_PER_ROW];
    ssp[tid] = p; ssf[tid] = f; ssn[tid] = n;
    __syncthreads();
    for (int off = 1; off < TILES_PER_ROW; off <<= 1) {
        int ap = tid >= off ? ssp[tid - off] : 0;
        int af = tid >= off ? ssf[tid - off] : 0;
        int an = tid >= off ? ssn[tid - off] : 0;
        __syncthreads();
        ssp[tid] += ap; ssf[tid] += af; ssn[tid] += an;
        __syncthreads();
    }
    int cp = ssp[TILES_PER_ROW - 1], cf = ssf[TILES_PER_ROW - 1], cn = ssn[TILES_PER_ROW - 1];
    bool useFp = cf > 0;
    int tile = r * TILES_PER_ROW + tid;
    oPos[tile] = ssp[tid] - p;
    oCh[tile] = useFp ? (ssf[tid] - f) : (ssn[tid] - n);
    if (tid == 0) {
        int cc = useFp ? cf : cn;
        rCp[r] = cp; rCc[r] = cc; rUseFp[r] = useFp ? 1 : 0;
        // magic multiplier: exact floor(l/d) for l < 2^18, d < 2^19 with k=40
        ull dp_ = (ull)(cp > 0 ? cp : 1);
        ull dc_ = (ull)(cc > 0 ? cc : 1);
        rMp[r] = ((1ull << 40) + dp_ - 1) / dp_;
        rMc[r] = ((1ull << 40) + dc_ - 1) / dc_;
    }
}

// ---------------- Pass D: stable scatter-compaction of xp (pos) and xf (chosen) --------
__global__ void scatter_kernel(const float* __restrict__ x,
                               const ull* __restrict__ maskT, const ull* __restrict__ maskX,
                               const ull* __restrict__ maskA,
                               const int* __restrict__ oPos, const int* __restrict__ oCh,
                               const int* __restrict__ rUseFp,
                               float* __restrict__ xp, float* __restrict__ xf) {
    int tile = blockIdx.x;
    int tid = threadIdx.x;
    int r = tile >> 7;  // / TILES_PER_ROW
    bool useFp = rUseFp[r] != 0;
    int widx = tile * WORDS_PER_TILE + (tid >> 3);
    int shift = (tid & 7) * 8;
    ull wa = maskA[widx];
    unsigned bT = (unsigned)(maskT[widx] >> shift) & 0xFF;
    unsigned bCh = useFp ? ((unsigned)((maskX[widx] & ~wa) >> shift) & 0xFF)
                         : ((unsigned)((~wa) >> shift) & 0xFF);
    const float4* x4 = (const float4*)x;
    int b4 = tile * (TILE / 4) + tid * 2;
    float4 a = x4[b4], b = x4[b4 + 1];
    float xv[8] = {a.x, a.y, a.z, a.w, b.x, b.y, b.z, b.w};
    int p = __popc(bT), c = __popc(bCh);
    __shared__ int s[TPB];
    int v = p | (c << 16);
    s[tid] = v;
    __syncthreads();
    for (int off = 1; off < TPB; off <<= 1) {
        int add = tid >= off ? s[tid - off] : 0;
        __syncthreads();
        s[tid] += add;
        __syncthreads();
    }
    int excl = s[tid] - v;
    int rL = r << LOG2L;
    int pw = rL + oPos[tile] + (excl & 0xFFFF);
    int cw = rL + oCh[tile] + (excl >> 16);
#pragma unroll
    for (int e = 0; e < 8; ++e) {
        if ((bT >> e) & 1) xp[pw++] = xv[e];
        if ((bCh >> e) & 1) xf[cw++] = xv[e];
    }
}

// ---------------- Pass E: streaming loss reduction ----------------
__global__ void loss_kernel(const float* __restrict__ x, const ull* __restrict__ maskT,
                            const float* __restrict__ xp, const float* __restrict__ xf,
                            const int* __restrict__ rCp, const int* __restrict__ rCc,
                            const ull* __restrict__ rMp, const ull* __restrict__ rMc,
                            double* __restrict__ acc, int n4) {
    int tid = threadIdx.x;
    int stride = gridDim.x * blockDim.x;
    float local = 0.0f;
    const float4* x4 = (const float4*)x;
    for (int i4 = blockIdx.x * blockDim.x + tid; i4 < n4; i4 += stride) {
        int g = i4 << 2;
        int r = g >> LOG2L;
        unsigned l = (unsigned)(g & (L - 1));
        float4 xv = x4[i4];
        unsigned tb = (unsigned)(maskT[g >> 6] >> (g & 63)) & 0xFu;
        int cp = rCp[r], cc = rCc[r];
        int rL = r << LOG2L;
        float dps[4], dfs[4];
        if (cp > 0) {
            ull M = rMp[r];
            unsigned d = (unsigned)cp;
            unsigned q = (unsigned)(((ull)l * M) >> 40);
            unsigned m0 = l - q * d;
            unsigned m1 = m0 + 1; if (m1 == d) m1 = 0;
            unsigned m2 = m1 + 1; if (m2 == d) m2 = 0;
            unsigned m3 = m2 + 1; if (m3 == d) m3 = 0;
            dps[0] = xp[rL + m0]; dps[1] = xp[rL + m1];
            dps[2] = xp[rL + m2]; dps[3] = xp[rL + m3];
        } else {
            dps[0] = dps[1] = dps[2] = dps[3] = 5.0f;
        }
        if (cc > 0) {
            ull M = rMc[r];
            unsigned d = (unsigned)cc;
            unsigned q = (unsigned)(((ull)l * M) >> 40);
            unsigned m0 = l - q * d;
            unsigned m1 = m0 + 1; if (m1 == d) m1 = 0;
            unsigned m2 = m1 + 1; if (m2 == d) m2 = 0;
            unsigned m3 = m2 + 1; if (m3 == d) m3 = 0;
            dfs[0] = xf[rL + m0]; dfs[1] = xf[rL + m1];
            dfs[2] = xf[rL + m2]; dfs[3] = xf[rL + m3];
        } else {
            dfs[0] = dfs[1] = dfs[2] = dfs[3] = -5.0f;
        }
        float xs[4] = {xv.x, xv.y, xv.z, xv.w};
#pragma unroll
        for (int k = 0; k < 4; ++k) {
            float sim = dps[k] * xs[k];
            // softplus(sim) - sim*t + [softplus(dp)-dp == softplus(-dp)] + 0.1*softplus(dp*df)
            float e = softplus_f(sim) + softplus_f(-dps[k]) + 0.1f * softplus_f(dps[k] * dfs[k]);
            if ((tb >> k) & 1) e -= sim;
            local += e;
        }
    }
    __shared__ double sd[TPB];
    sd[tid] = (double)local;
    __syncthreads();
    for (int off = TPB / 2; off > 0; off >>= 1) {
        if (tid < off) sd[tid] += sd[tid + off];
        __syncthreads();
    }
    if (tid == 0) atomicAdd(acc, sd[0]);
}

__global__ void finalize_kernel(const double* __restrict__ acc, float* __restrict__ out,
                                int ntot) {
    out[0] = (float)(acc[0] / (double)ntot);
}

extern "C" void kernel_launch(void* const* d_in, const int* in_sizes, int n_in,
                              void* d_out, int out_size, void* d_ws, size_t ws_size,
                              hipStream_t stream) {
    const float* x = (const float*)d_in[0];  // input
    const float* t = (const float*)d_in[1];  // target
    float* out = (float*)d_out;

    int ntot = in_sizes[0];          // 12,582,912
    int R = ntot >> LOG2L;           // 48
    int numTiles = ntot / TILE;      // 6144
    int nwords = ntot / 64;          // 196,608
    int nwords4 = nwords / 4;        // 49,152

    char* ws = (char*)d_ws;
    size_t off = 0;
    auto alloc = [&](size_t bytes) {
        size_t p = off;
        off = (off + bytes + 255) & ~(size_t)255;
        return (void*)(ws + p);
    };
    double* acc = (double*)alloc(sizeof(double));
    ull* maskT = (ull*)alloc((size_t)nwords * 8);
    ull* maskX = (ull*)alloc((size_t)nwords * 8);
    ull* maskH = (ull*)alloc((size_t)nwords * 8);
    ull* maskA = (ull*)alloc((size_t)nwords * 8);
    int* oPos = (int*)alloc(numTiles * sizeof(int));
    int* oCh  = (int*)alloc(numTiles * sizeof(int));
    int* rCp = (int*)alloc(R * sizeof(int));
    int* rCc = (int*)alloc(R * sizeof(int));
    int* rUseFp = (int*)alloc(R * sizeof(int));
    ull* rMp = (ull*)alloc(R * sizeof(ull));
    ull* rMc = (ull*)alloc(R * sizeof(ull));
    float* xp = (float*)alloc((size_t)ntot * sizeof(float));
    float* xf = (float*)alloc((size_t)ntot * sizeof(float));

    (void)hipMemsetAsync(acc, 0, sizeof(double), stream);

    mask_kernel<<<768, TPB, 0, stream>>>(x, t, maskT, maskX, nwords4);
    dilate_h_kernel<<<nwords / TPB, TPB, 0, stream>>>(maskT, maskH, nwords);
    dilate_v_kernel<<<nwords / TPB, TPB, 0, stream>>>(maskH, maskA, nwords);
    count_scan_kernel<<<R, TILES_PER_ROW, 0, stream>>>(maskT, maskX, maskA, oPos, oCh,
                                                       rCp, rCc, rMp, rMc, rUseFp);
    scatter_kernel<<<numTiles, TPB, 0, stream>>>(x, maskT, maskX, maskA, oPos, oCh, rUseFp,
                                                 xp, xf);
    loss_kernel<<<2048, TPB, 0, stream>>>(x, maskT, xp, xf, rCp, rCc, rMp, rMc, acc,
                                          ntot / 4);
    finalize_kernel<<<1, 1, 0, stream>>>(acc, out, ntot);
}

// Round 4
// 178.395 us; speedup vs baseline: 1.8841x; 1.0888x over previous
//
#include <hip/hip_runtime.h>
#include <math.h>

// Problem constants (B=16, C=3, H=W=512) -> 48 "rows" of L = 262144 elements.
constexpr int W = 512;
constexpr int HIMG = 512;
constexpr int L = 1 << 18;               // elements per row
constexpr int LOG2L = 18;
constexpr int TPB = 256;
constexpr int TILE = 2048;               // elements per scatter tile
constexpr int TILES_PER_ROW = L / TILE;  // 128
constexpr int WORDS_PER_ROW = L / 64;    // 4096
constexpr int WORDS_PER_TILE = TILE / 64; // 32
constexpr int LBLK = 32;                 // loss blocks per row
constexpr int CHUNK = L / LBLK;          // 8192 elements per loss block
constexpr int LIT = CHUNK / (TPB * 4);   // 8 float4 iterations per thread

typedef unsigned long long ull;

// softplus via native v_exp_f32 / v_log_f32 (abs err ~1e-6; threshold 3.6e-2)
__device__ __forceinline__ float softplus_f(float v) {
    return fmaxf(v, 0.0f) +
           0.6931471805599453f *
               __builtin_amdgcn_logf(1.0f + __builtin_amdgcn_exp2f(-fabsf(v) * 1.4426950408889634f));
}

__device__ __forceinline__ ull hdil7(ull prev, ull cur, ull next) {
    ull r = cur;
    r |= (cur >> 1) | (next << 63);
    r |= (cur >> 2) | (next << 62);
    r |= (cur >> 3) | (next << 61);
    r |= (cur << 1) | (prev >> 63);
    r |= (cur << 2) | (prev >> 62);
    r |= (cur << 3) | (prev >> 61);
    return r;
}

template <typename T>
__device__ __forceinline__ T sel8(const T* a, int k) {
    return k == 0 ? a[0] : k == 1 ? a[1] : k == 2 ? a[2] : k == 3 ? a[3]
         : k == 4 ? a[4] : k == 5 ? a[5] : k == 6 ? a[6] : a[7];
}

// ---------------- Pass A: masks + horizontal 7-dilation, one scanline per wave-iter ----
__global__ void mask_dilh_kernel(const float* __restrict__ x, const float* __restrict__ t,
                                 ull* __restrict__ maskT, ull* __restrict__ maskX,
                                 ull* __restrict__ maskH, double* __restrict__ acc,
                                 int nScan) {
    if (blockIdx.x == 0 && threadIdx.x == 0) acc[0] = 0.0;  // zero accumulator for loss pass
    int lane = threadIdx.x & 63;
    int wave = (blockIdx.x * TPB + threadIdx.x) >> 6;
    int nW = (gridDim.x * TPB) >> 6;
    for (int s = wave; s < nScan; s += nW) {
        int eb = s << 9;  // element base of this 512-wide scanline
        ull wt[8], wx[8], h[8];
#pragma unroll
        for (int k = 0; k < 8; ++k) {
            wt[k] = __ballot(t[eb + k * 64 + lane] > 0.0f);
            wx[k] = __ballot(x[eb + k * 64 + lane] > 0.0f);
        }
#pragma unroll
        for (int k = 0; k < 8; ++k) {
            ull cur = wt[k];
            ull prev = k ? wt[k - 1]
                         : ((((cur >> 1) & 1ull) << 63) | (((cur >> 2) & 1ull) << 62) |
                            (((cur >> 3) & 1ull) << 61));
            ull next = (k < 7) ? wt[k + 1]
                               : (((cur >> 62) & 1ull) | (((cur >> 61) & 1ull) << 1) |
                                  (((cur >> 60) & 1ull) << 2));
            h[k] = hdil7(prev, cur, next);
        }
        int w0 = s << 3;
        int k = lane & 7;
        if (lane < 8) maskT[w0 + k] = sel8(wt, k);
        else if (lane < 16) maskX[w0 + k] = sel8(wx, k);
        else if (lane < 24) maskH[w0 + k] = sel8(h, k);
    }
}

// ---------------- Pass B: vertical 7-tall OR (reflect) ----------------
__global__ void dilate_v_kernel(const ull* __restrict__ maskH, ull* __restrict__ maskA,
                                int nwords) {
    int w = blockIdx.x * blockDim.x + threadIdx.x;
    if (w >= nwords) return;
    int wimg = w & (WORDS_PER_ROW - 1);
    int scan = wimg >> 3;
    int wcol = wimg & 7;
    int base = w - wimg;
    ull out = 0;
#pragma unroll
    for (int d = -3; d <= 3; ++d) {
        int ii = scan + d;
        ii = ii < 0 ? -ii : (ii > HIMG - 1 ? 2 * (HIMG - 1) - ii : ii);
        out |= maskH[base + ii * 8 + wcol];
    }
    maskA[w] = out;
}

// ---------------- Pass C: per-row tile counts + scan + magic divisors ----------------
// 256 threads/block, coalesced word loads -> per-word popcounts in LDS -> tile sums -> scan.
__global__ void count_scan_kernel(const ull* __restrict__ maskT, const ull* __restrict__ maskX,
                                  const ull* __restrict__ maskA,
                                  int* __restrict__ oPos, int* __restrict__ oCh,
                                  int* __restrict__ rCp, int* __restrict__ rCc,
                                  ull* __restrict__ rMp, ull* __restrict__ rMc,
                                  int* __restrict__ rUseFp) {
    int r = blockIdx.x;
    int tid = threadIdx.x;  // 0..255
    __shared__ unsigned char pw[WORDS_PER_ROW], fw[WORDS_PER_ROW], nw[WORDS_PER_ROW];
    int base = r * WORDS_PER_ROW;
#pragma unroll
    for (int c = 0; c < WORDS_PER_ROW / TPB; ++c) {  // 16 coalesced rounds
        int w = c * TPB + tid;
        ull wt = maskT[base + w], wx = maskX[base + w], wa = maskA[base + w];
        pw[w] = (unsigned char)__popcll(wt);
        fw[w] = (unsigned char)__popcll(wx & ~wa);
        nw[w] = (unsigned char)(64 - __popcll(wa));
    }
    __syncthreads();
    __shared__ int ssp[TILES_PER_ROW], ssf[TILES_PER_ROW], ssn[TILES_PER_ROW];
    int myp = 0, myf = 0, myn = 0;
    if (tid < TILES_PER_ROW) {
        int wb = tid * WORDS_PER_TILE;
#pragma unroll 8
        for (int k = 0; k < WORDS_PER_TILE; ++k) {
            myp += pw[wb + k]; myf += fw[wb + k]; myn += nw[wb + k];
        }
        ssp[tid] = myp; ssf[tid] = myf; ssn[tid] = myn;
    }
    __syncthreads();
    for (int off = 1; off < TILES_PER_ROW; off <<= 1) {
        int ap = 0, af = 0, an = 0;
        bool act = (tid < TILES_PER_ROW && tid >= off);
        if (act) { ap = ssp[tid - off]; af = ssf[tid - off]; an = ssn[tid - off]; }
        __syncthreads();
        if (act) { ssp[tid] += ap; ssf[tid] += af; ssn[tid] += an; }
        __syncthreads();
    }
    if (tid < TILES_PER_ROW) {
        int cp = ssp[TILES_PER_ROW - 1], cf = ssf[TILES_PER_ROW - 1], cn = ssn[TILES_PER_ROW - 1];
        bool useFp = cf > 0;
        int tile = r * TILES_PER_ROW + tid;
        oPos[tile] = ssp[tid] - myp;
        oCh[tile] = useFp ? (ssf[tid] - myf) : (ssn[tid] - myn);
        if (tid == 0) {
            int cc = useFp ? cf : cn;
            rCp[r] = cp; rCc[r] = cc; rUseFp[r] = useFp ? 1 : 0;
            ull dp_ = (ull)(cp > 0 ? cp : 1);
            ull dc_ = (ull)(cc > 0 ? cc : 1);
            rMp[r] = ((1ull << 40) + dp_ - 1) / dp_;  // exact floor(l/d), l < 2^18
            rMc[r] = ((1ull << 40) + dc_ - 1) / dc_;
        }
    }
}

// ---------------- Pass D: stable scatter-compaction ----------------
__global__ void scatter_kernel(const float* __restrict__ x,
                               const ull* __restrict__ maskT, const ull* __restrict__ maskX,
                               const ull* __restrict__ maskA,
                               const int* __restrict__ oPos, const int* __restrict__ oCh,
                               const int* __restrict__ rUseFp,
                               float* __restrict__ xp, float* __restrict__ xf) {
    int tile = blockIdx.x;
    int tid = threadIdx.x;
    int r = tile >> 7;
    bool useFp = rUseFp[r] != 0;
    int widx = tile * WORDS_PER_TILE + (tid >> 3);
    int shift = (tid & 7) * 8;
    ull wa = maskA[widx];
    unsigned bT = (unsigned)(maskT[widx] >> shift) & 0xFF;
    unsigned bCh = useFp ? ((unsigned)((maskX[widx] & ~wa) >> shift) & 0xFF)
                         : ((unsigned)((~wa) >> shift) & 0xFF);
    const float4* x4 = (const float4*)x;
    int b4 = tile * (TILE / 4) + tid * 2;
    float4 a = x4[b4], b = x4[b4 + 1];
    float xv[8] = {a.x, a.y, a.z, a.w, b.x, b.y, b.z, b.w};
    int p = __popc(bT), c = __popc(bCh);
    __shared__ int s[TPB];
    int v = p | (c << 16);
    s[tid] = v;
    __syncthreads();
    for (int off = 1; off < TPB; off <<= 1) {
        int add = tid >= off ? s[tid - off] : 0;
        __syncthreads();
        s[tid] += add;
        __syncthreads();
    }
    int excl = s[tid] - v;
    int rL = r << LOG2L;
    int pw = rL + oPos[tile] + (excl & 0xFFFF);
    int cw = rL + oCh[tile] + (excl >> 16);
#pragma unroll
    for (int e = 0; e < 8; ++e) {
        if ((bT >> e) & 1) xp[pw++] = xv[e];
        if ((bCh >> e) & 1) xf[cw++] = xv[e];
    }
}

// ---------------- Pass E: loss; one contiguous row-aligned chunk per block ----------------
__global__ __launch_bounds__(TPB)
void loss_kernel(const float* __restrict__ x, const ull* __restrict__ maskT,
                 const float* __restrict__ xp, const float* __restrict__ xf,
                 const int* __restrict__ rCp, const int* __restrict__ rCc,
                 const ull* __restrict__ rMp, const ull* __restrict__ rMc,
                 double* __restrict__ acc) {
    int r = blockIdx.x >> 5;               // 32 blocks per row
    int cb = (blockIdx.x & 31) * CHUNK;    // chunk base (elements, within row)
    int rL = r << LOG2L;
    int cp = rCp[r], cc = rCc[r];          // wave-uniform: scalar loads, hoisted
    ull Mp = rMp[r], Mc = rMc[r];
    const float4* x4 = (const float4*)(x + rL + cb);
    const float* xpr = xp + rL;
    const float* xfr = xf + rL;
    const ull* mtr = maskT + (rL >> 6);
    float local = 0.0f;
#pragma unroll
    for (int it = 0; it < LIT; ++it) {
        int o4 = it * TPB + threadIdx.x;
        unsigned l = (unsigned)(cb + (o4 << 2));
        float4 xv = x4[o4];
        unsigned tb = (unsigned)(mtr[l >> 6] >> (l & 63)) & 0xFu;
        float dps[4], dfs[4];
        if (cp > 0) {
            unsigned d = (unsigned)cp;
            unsigned q = (unsigned)(((ull)l * Mp) >> 40);
            unsigned m0 = l - q * d;
            unsigned m1 = m0 + 1; if (m1 == d) m1 = 0;
            unsigned m2 = m1 + 1; if (m2 == d) m2 = 0;
            unsigned m3 = m2 + 1; if (m3 == d) m3 = 0;
            dps[0] = xpr[m0]; dps[1] = xpr[m1]; dps[2] = xpr[m2]; dps[3] = xpr[m3];
        } else {
            dps[0] = dps[1] = dps[2] = dps[3] = 5.0f;
        }
        if (cc > 0) {
            unsigned d = (unsigned)cc;
            unsigned q = (unsigned)(((ull)l * Mc) >> 40);
            unsigned m0 = l - q * d;
            unsigned m1 = m0 + 1; if (m1 == d) m1 = 0;
            unsigned m2 = m1 + 1; if (m2 == d) m2 = 0;
            unsigned m3 = m2 + 1; if (m3 == d) m3 = 0;
            dfs[0] = xfr[m0]; dfs[1] = xfr[m1]; dfs[2] = xfr[m2]; dfs[3] = xfr[m3];
        } else {
            dfs[0] = dfs[1] = dfs[2] = dfs[3] = -5.0f;
        }
        float xs[4] = {xv.x, xv.y, xv.z, xv.w};
#pragma unroll
        for (int k = 0; k < 4; ++k) {
            float sim = dps[k] * xs[k];
            float e = softplus_f(sim) + softplus_f(-dps[k]) + 0.1f * softplus_f(dps[k] * dfs[k]);
            if ((tb >> k) & 1) e -= sim;
            local += e;
        }
    }
    __shared__ double sd[TPB];
    int tid = threadIdx.x;
    sd[tid] = (double)local;
    __syncthreads();
    for (int off = TPB / 2; off > 0; off >>= 1) {
        if (tid < off) sd[tid] += sd[tid + off];
        __syncthreads();
    }
    if (tid == 0) atomicAdd(acc, sd[0]);
}

__global__ void finalize_kernel(const double* __restrict__ acc, float* __restrict__ out,
                                int ntot) {
    out[0] = (float)(acc[0] / (double)ntot);
}

extern "C" void kernel_launch(void* const* d_in, const int* in_sizes, int n_in,
                              void* d_out, int out_size, void* d_ws, size_t ws_size,
                              hipStream_t stream) {
    const float* x = (const float*)d_in[0];
    const float* t = (const float*)d_in[1];
    float* out = (float*)d_out;

    int ntot = in_sizes[0];          // 12,582,912
    int R = ntot >> LOG2L;           // 48
    int numTiles = ntot / TILE;      // 6144
    int nwords = ntot / 64;          // 196,608
    int nScan = ntot / W;            // 24,576 scanlines

    char* ws = (char*)d_ws;
    size_t off = 0;
    auto alloc = [&](size_t bytes) {
        size_t p = off;
        off = (off + bytes + 255) & ~(size_t)255;
        return (void*)(ws + p);
    };
    double* acc = (double*)alloc(sizeof(double));
    ull* maskT = (ull*)alloc((size_t)nwords * 8);
    ull* maskX = (ull*)alloc((size_t)nwords * 8);
    ull* maskH = (ull*)alloc((size_t)nwords * 8);
    ull* maskA = (ull*)alloc((size_t)nwords * 8);
    int* oPos = (int*)alloc(numTiles * sizeof(int));
    int* oCh  = (int*)alloc(numTiles * sizeof(int));
    int* rCp = (int*)alloc(R * sizeof(int));
    int* rCc = (int*)alloc(R * sizeof(int));
    int* rUseFp = (int*)alloc(R * sizeof(int));
    ull* rMp = (ull*)alloc(R * sizeof(ull));
    ull* rMc = (ull*)alloc(R * sizeof(ull));
    float* xp = (float*)alloc((size_t)ntot * sizeof(float));
    float* xf = (float*)alloc((size_t)ntot * sizeof(float));

    mask_dilh_kernel<<<1536, TPB, 0, stream>>>(x, t, maskT, maskX, maskH, acc, nScan);
    dilate_v_kernel<<<nwords / TPB, TPB, 0, stream>>>(maskH, maskA, nwords);
    count_scan_kernel<<<R, TPB, 0, stream>>>(maskT, maskX, maskA, oPos, oCh,
                                             rCp, rCc, rMp, rMc, rUseFp);
    scatter_kernel<<<numTiles, TPB, 0, stream>>>(x, maskT, maskX, maskA, oPos, oCh, rUseFp,
                                                 xp, xf);
    loss_kernel<<<R * LBLK, TPB, 0, stream>>>(x, maskT, xp, xf, rCp, rCc, rMp, rMc, acc);
    finalize_kernel<<<1, 1, 0, stream>>>(acc, out, ntot);
}

// Round 5
// 176.145 us; speedup vs baseline: 1.9082x; 1.0128x over previous
//
#include <hip/hip_runtime.h>
#include <math.h>

// Problem constants (B=16, C=3, H=W=512) -> 48 "rows" (images) of L = 262144 elements.
constexpr int W = 512;
constexpr int HIMG = 512;
constexpr int L = 1 << 18;               // elements per row
constexpr int LOG2L = 18;
constexpr int TPB = 256;
constexpr int TILE = 2048;               // elements per scatter tile
constexpr int TILES_PER_ROW = L / TILE;  // 128
constexpr int WORDS_PER_ROW = L / 64;    // 4096
constexpr int WORDS_PER_TILE = TILE / 64; // 32
constexpr int LBLK = 32;                 // loss blocks per row
constexpr int CHUNK = L / LBLK;          // 8192 elements per loss block
constexpr int LIT = CHUNK / (TPB * 4);   // 8 float4 iterations per thread

typedef unsigned long long ull;

// softplus via native v_exp_f32 / v_log_f32 (abs err ~1e-6; threshold 3.6e-2)
__device__ __forceinline__ float softplus_f(float v) {
    return fmaxf(v, 0.0f) +
           0.6931471805599453f *
               __builtin_amdgcn_logf(1.0f + __builtin_amdgcn_exp2f(-fabsf(v) * 1.4426950408889634f));
}

__device__ __forceinline__ ull hdil7(ull prev, ull cur, ull next) {
    ull r = cur;
    r |= (cur >> 1) | (next << 63);
    r |= (cur >> 2) | (next << 62);
    r |= (cur >> 3) | (next << 61);
    r |= (cur << 1) | (prev >> 63);
    r |= (cur << 2) | (prev >> 62);
    r |= (cur << 3) | (prev >> 61);
    return r;
}

template <typename T>
__device__ __forceinline__ T sel8(const T* a, int k) {
    return k == 0 ? a[0] : k == 1 ? a[1] : k == 2 ? a[2] : k == 3 ? a[3]
         : k == 4 ? a[4] : k == 5 ? a[5] : k == 6 ? a[6] : a[7];
}

// ---------------- Pass A: masks + horizontal 7-dilation, one scanline per wave-iter ----
__global__ void mask_dilh_kernel(const float* __restrict__ x, const float* __restrict__ t,
                                 ull* __restrict__ maskT, ull* __restrict__ maskX,
                                 ull* __restrict__ maskH, float* __restrict__ out,
                                 int nScan) {
    if (blockIdx.x == 0 && threadIdx.x == 0) out[0] = 0.0f;  // d_out is poisoned; zero it
    int lane = threadIdx.x & 63;
    int wave = (blockIdx.x * TPB + threadIdx.x) >> 6;
    int nW = (gridDim.x * TPB) >> 6;
    for (int s = wave; s < nScan; s += nW) {
        int eb = s << 9;  // element base of this 512-wide scanline
        ull wt[8], wx[8], h[8];
#pragma unroll
        for (int k = 0; k < 8; ++k) {
            wt[k] = __ballot(t[eb + k * 64 + lane] > 0.0f);
            wx[k] = __ballot(x[eb + k * 64 + lane] > 0.0f);
        }
#pragma unroll
        for (int k = 0; k < 8; ++k) {
            ull cur = wt[k];
            ull prev = k ? wt[k - 1]
                         : ((((cur >> 1) & 1ull) << 63) | (((cur >> 2) & 1ull) << 62) |
                            (((cur >> 3) & 1ull) << 61));
            ull next = (k < 7) ? wt[k + 1]
                               : (((cur >> 62) & 1ull) | (((cur >> 61) & 1ull) << 1) |
                                  (((cur >> 60) & 1ull) << 2));
            h[k] = hdil7(prev, cur, next);
        }
        int w0 = s << 3;
        int k = lane & 7;
        if (lane < 8) maskT[w0 + k] = sel8(wt, k);
        else if (lane < 16) maskX[w0 + k] = sel8(wx, k);
        else if (lane < 24) maskH[w0 + k] = sel8(h, k);
    }
}

// ---------------- Pass B: fused vertical dilation + counts + scan (one block per row) ----
__global__ __launch_bounds__(TPB)
void dilv_count_kernel(const ull* __restrict__ maskT, const ull* __restrict__ maskX,
                       const ull* __restrict__ maskH, ull* __restrict__ maskA,
                       int* __restrict__ oPos, int* __restrict__ oCh,
                       int* __restrict__ rCp, int* __restrict__ rCc,
                       ull* __restrict__ rMp, ull* __restrict__ rMc,
                       int* __restrict__ rUseFp) {
    int r = blockIdx.x;
    int tid = threadIdx.x;  // 0..255
    __shared__ ull sh[WORDS_PER_ROW];                                  // 32 KB: maskH row
    __shared__ unsigned char pw[WORDS_PER_ROW], fw[WORDS_PER_ROW], nw[WORDS_PER_ROW];
    int base = r * WORDS_PER_ROW;
#pragma unroll
    for (int c = 0; c < WORDS_PER_ROW / TPB; ++c) {
        int w = c * TPB + tid;
        sh[w] = maskH[base + w];
    }
    __syncthreads();
#pragma unroll
    for (int c = 0; c < WORDS_PER_ROW / TPB; ++c) {
        int w = c * TPB + tid;
        int scan = w >> 3, col = w & 7;
        ull wa = 0;
#pragma unroll
        for (int d = -3; d <= 3; ++d) {
            int ii = scan + d;
            ii = ii < 0 ? -ii : (ii > HIMG - 1 ? 2 * (HIMG - 1) - ii : ii);
            wa |= sh[ii * 8 + col];
        }
        maskA[base + w] = wa;
        ull wt = maskT[base + w], wx = maskX[base + w];
        pw[w] = (unsigned char)__popcll(wt);
        fw[w] = (unsigned char)__popcll(wx & ~wa);
        nw[w] = (unsigned char)(64 - __popcll(wa));
    }
    __syncthreads();
    __shared__ int ssp[TILES_PER_ROW], ssf[TILES_PER_ROW], ssn[TILES_PER_ROW];
    int myp = 0, myf = 0, myn = 0;
    if (tid < TILES_PER_ROW) {
        int wb = tid * WORDS_PER_TILE;
#pragma unroll 8
        for (int k = 0; k < WORDS_PER_TILE; ++k) {
            myp += pw[wb + k]; myf += fw[wb + k]; myn += nw[wb + k];
        }
        ssp[tid] = myp; ssf[tid] = myf; ssn[tid] = myn;
    }
    __syncthreads();
    for (int off = 1; off < TILES_PER_ROW; off <<= 1) {
        int ap = 0, af = 0, an = 0;
        bool act = (tid < TILES_PER_ROW && tid >= off);
        if (act) { ap = ssp[tid - off]; af = ssf[tid - off]; an = ssn[tid - off]; }
        __syncthreads();
        if (act) { ssp[tid] += ap; ssf[tid] += af; ssn[tid] += an; }
        __syncthreads();
    }
    if (tid < TILES_PER_ROW) {
        int cp = ssp[TILES_PER_ROW - 1], cf = ssf[TILES_PER_ROW - 1], cn = ssn[TILES_PER_ROW - 1];
        bool useFp = cf > 0;
        int tile = r * TILES_PER_ROW + tid;
        oPos[tile] = ssp[tid] - myp;
        oCh[tile] = useFp ? (ssf[tid] - myf) : (ssn[tid] - myn);
        if (tid == 0) {
            int cc = useFp ? cf : cn;
            rCp[r] = cp; rCc[r] = cc; rUseFp[r] = useFp ? 1 : 0;
            ull dp_ = (ull)(cp > 0 ? cp : 1);
            ull dc_ = (ull)(cc > 0 ? cc : 1);
            rMp[r] = ((1ull << 40) + dp_ - 1) / dp_;  // exact floor(l/d), l < 2^18
            rMc[r] = ((1ull << 40) + dc_ - 1) / dc_;
        }
    }
}

// ---------------- Pass C: stable scatter-compaction ----------------
__global__ void scatter_kernel(const float* __restrict__ x,
                               const ull* __restrict__ maskT, const ull* __restrict__ maskX,
                               const ull* __restrict__ maskA,
                               const int* __restrict__ oPos, const int* __restrict__ oCh,
                               const int* __restrict__ rUseFp,
                               float* __restrict__ xp, float* __restrict__ xf) {
    int tile = blockIdx.x;
    int tid = threadIdx.x;
    int r = tile >> 7;
    bool useFp = rUseFp[r] != 0;
    int widx = tile * WORDS_PER_TILE + (tid >> 3);
    int shift = (tid & 7) * 8;
    ull wa = maskA[widx];
    unsigned bT = (unsigned)(maskT[widx] >> shift) & 0xFF;
    unsigned bCh = useFp ? ((unsigned)((maskX[widx] & ~wa) >> shift) & 0xFF)
                         : ((unsigned)((~wa) >> shift) & 0xFF);
    const float4* x4 = (const float4*)x;
    int b4 = tile * (TILE / 4) + tid * 2;
    float4 a = x4[b4], b = x4[b4 + 1];
    float xv[8] = {a.x, a.y, a.z, a.w, b.x, b.y, b.z, b.w};
    int p = __popc(bT), c = __popc(bCh);
    __shared__ int s[TPB];
    int v = p | (c << 16);
    s[tid] = v;
    __syncthreads();
    for (int off = 1; off < TPB; off <<= 1) {
        int add = tid >= off ? s[tid - off] : 0;
        __syncthreads();
        s[tid] += add;
        __syncthreads();
    }
    int excl = s[tid] - v;
    int rL = r << LOG2L;
    int pwi = rL + oPos[tile] + (excl & 0xFFFF);
    int cwi = rL + oCh[tile] + (excl >> 16);
#pragma unroll
    for (int e = 0; e < 8; ++e) {
        if ((bT >> e) & 1) xp[pwi++] = xv[e];
        if ((bCh >> e) & 1) xf[cwi++] = xv[e];
    }
}

// ---------------- Pass D: loss; one contiguous row-aligned chunk per block ----------------
__global__ __launch_bounds__(TPB)
void loss_kernel(const float* __restrict__ x, const ull* __restrict__ maskT,
                 const float* __restrict__ xp, const float* __restrict__ xf,
                 const int* __restrict__ rCp, const int* __restrict__ rCc,
                 const ull* __restrict__ rMp, const ull* __restrict__ rMc,
                 float* __restrict__ out, double inv_ntot) {
    int r = blockIdx.x >> 5;               // 32 blocks per row
    int cb = (blockIdx.x & 31) * CHUNK;    // chunk base (elements, within row)
    int rL = r << LOG2L;
    int cp = rCp[r], cc = rCc[r];          // wave-uniform: scalar loads, hoisted
    ull Mp = rMp[r], Mc = rMc[r];
    const float4* x4 = (const float4*)(x + rL + cb);
    const float* xpr = xp + rL;
    const float* xfr = xf + rL;
    const ull* mtr = maskT + (rL >> 6);
    float local = 0.0f;
#pragma unroll
    for (int it = 0; it < LIT; ++it) {
        int o4 = it * TPB + threadIdx.x;
        unsigned l = (unsigned)(cb + (o4 << 2));
        float4 xv = x4[o4];
        unsigned tb = (unsigned)(mtr[l >> 6] >> (l & 63)) & 0xFu;
        float dps[4], dfs[4];
        if (cp > 0) {
            unsigned d = (unsigned)cp;
            unsigned q = (unsigned)(((ull)l * Mp) >> 40);
            unsigned m0 = l - q * d;
            unsigned m1 = m0 + 1; if (m1 == d) m1 = 0;
            unsigned m2 = m1 + 1; if (m2 == d) m2 = 0;
            unsigned m3 = m2 + 1; if (m3 == d) m3 = 0;
            dps[0] = xpr[m0]; dps[1] = xpr[m1]; dps[2] = xpr[m2]; dps[3] = xpr[m3];
        } else {
            dps[0] = dps[1] = dps[2] = dps[3] = 5.0f;
        }
        if (cc > 0) {
            unsigned d = (unsigned)cc;
            unsigned q = (unsigned)(((ull)l * Mc) >> 40);
            unsigned m0 = l - q * d;
            unsigned m1 = m0 + 1; if (m1 == d) m1 = 0;
            unsigned m2 = m1 + 1; if (m2 == d) m2 = 0;
            unsigned m3 = m2 + 1; if (m3 == d) m3 = 0;
            dfs[0] = xfr[m0]; dfs[1] = xfr[m1]; dfs[2] = xfr[m2]; dfs[3] = xfr[m3];
        } else {
            dfs[0] = dfs[1] = dfs[2] = dfs[3] = -5.0f;
        }
        float xs[4] = {xv.x, xv.y, xv.z, xv.w};
#pragma unroll
        for (int k = 0; k < 4; ++k) {
            float sim = dps[k] * xs[k];
            float e = softplus_f(sim) + softplus_f(-dps[k]) + 0.1f * softplus_f(dps[k] * dfs[k]);
            if ((tb >> k) & 1) e -= sim;
            local += e;
        }
    }
    __shared__ double sd[TPB];
    int tid = threadIdx.x;
    sd[tid] = (double)local;
    __syncthreads();
    for (int off = TPB / 2; off > 0; off >>= 1) {
        if (tid < off) sd[tid] += sd[tid + off];
        __syncthreads();
    }
    if (tid == 0) atomicAdd(out, (float)(sd[0] * inv_ntot));
}

extern "C" void kernel_launch(void* const* d_in, const int* in_sizes, int n_in,
                              void* d_out, int out_size, void* d_ws, size_t ws_size,
                              hipStream_t stream) {
    const float* x = (const float*)d_in[0];
    const float* t = (const float*)d_in[1];
    float* out = (float*)d_out;

    int ntot = in_sizes[0];          // 12,582,912
    int R = ntot >> LOG2L;           // 48
    int numTiles = ntot / TILE;      // 6144
    int nwords = ntot / 64;          // 196,608
    int nScan = ntot / W;            // 24,576 scanlines

    char* ws = (char*)d_ws;
    size_t off = 0;
    auto alloc = [&](size_t bytes) {
        size_t p = off;
        off = (off + bytes + 255) & ~(size_t)255;
        return (void*)(ws + p);
    };
    ull* maskT = (ull*)alloc((size_t)nwords * 8);
    ull* maskX = (ull*)alloc((size_t)nwords * 8);
    ull* maskH = (ull*)alloc((size_t)nwords * 8);
    ull* maskA = (ull*)alloc((size_t)nwords * 8);
    int* oPos = (int*)alloc(numTiles * sizeof(int));
    int* oCh  = (int*)alloc(numTiles * sizeof(int));
    int* rCp = (int*)alloc(R * sizeof(int));
    int* rCc = (int*)alloc(R * sizeof(int));
    int* rUseFp = (int*)alloc(R * sizeof(int));
    ull* rMp = (ull*)alloc(R * sizeof(ull));
    ull* rMc = (ull*)alloc(R * sizeof(ull));
    float* xp = (float*)alloc((size_t)ntot * sizeof(float));
    float* xf = (float*)alloc((size_t)ntot * sizeof(float));

    mask_dilh_kernel<<<1536, TPB, 0, stream>>>(x, t, maskT, maskX, maskH, out, nScan);
    dilv_count_kernel<<<R, TPB, 0, stream>>>(maskT, maskX, maskH, maskA, oPos, oCh,
                                             rCp, rCc, rMp, rMc, rUseFp);
    scatter_kernel<<<numTiles, TPB, 0, stream>>>(x, maskT, maskX, maskA, oPos, oCh, rUseFp,
                                                 xp, xf);
    loss_kernel<<<R * LBLK, TPB, 0, stream>>>(x, maskT, xp, xf, rCp, rCc, rMp, rMc, out,
                                              1.0 / (double)ntot);
}

// Round 6
// 171.629 us; speedup vs baseline: 1.9584x; 1.0263x over previous
//
#include <hip/hip_runtime.h>
#include <math.h>

// Problem constants (B=16, C=3, H=W=512) -> 48 "rows" (images) of L = 262144 elements.
constexpr int W = 512;
constexpr int HIMG = 512;
constexpr int L = 1 << 18;                // elements per row
constexpr int LOG2L = 18;
constexpr int TPB = 256;
constexpr int TILE = 2048;                // elements per scatter tile (= 4 scanlines)
constexpr int TILES_PER_ROW = L / TILE;   // 128
constexpr int WORDS_PER_TILE = TILE / 64; // 32
constexpr int SPB = 32;                   // scanlines per fused-mask block
constexpr int HALO = 3;
constexpr int HBUF = SPB + 2 * HALO;      // 38
constexpr int BLK_PER_IMG = HIMG / SPB;   // 16
constexpr int LBLK = 32;                  // loss blocks per row
constexpr int CHUNK = L / LBLK;           // 8192 elements per loss block
constexpr int LIT = CHUNK / (TPB * 4);    // 8 float4 iterations per thread

typedef unsigned long long ull;

// softplus via native v_exp_f32 / v_log_f32 (abs err ~1e-6; threshold 3.6e-2)
__device__ __forceinline__ float softplus_f(float v) {
    return fmaxf(v, 0.0f) +
           0.6931471805599453f *
               __builtin_amdgcn_logf(1.0f + __builtin_amdgcn_exp2f(-fabsf(v) * 1.4426950408889634f));
}

__device__ __forceinline__ ull hdil7(ull prev, ull cur, ull next) {
    ull r = cur;
    r |= (cur >> 1) | (next << 63);
    r |= (cur >> 2) | (next << 62);
    r |= (cur >> 3) | (next << 61);
    r |= (cur << 1) | (prev >> 63);
    r |= (cur << 2) | (prev >> 62);
    r |= (cur << 3) | (prev >> 61);
    return r;
}

template <typename T>
__device__ __forceinline__ T sel8(const T* a, int k) {
    return k == 0 ? a[0] : k == 1 ? a[1] : k == 2 ? a[2] : k == 3 ? a[3]
         : k == 4 ? a[4] : k == 5 ? a[5] : k == 6 ? a[6] : a[7];
}

// ------ K1: fused masks + 7x7 dilation + per-tile counts. One block = 32 scanlines. ------
__global__ __launch_bounds__(TPB)
void fused_mask_kernel(const float* __restrict__ x, const float* __restrict__ t,
                       ull* __restrict__ mT, ull* __restrict__ mFp, ull* __restrict__ mNeg,
                       int* __restrict__ cPos, int* __restrict__ cFp, int* __restrict__ cNeg,
                       float* __restrict__ out) {
    if (blockIdx.x == 0 && threadIdx.x == 0) out[0] = 0.0f;  // d_out is poisoned; zero it
    int b = blockIdx.x;
    int img = b >> 4;              // BLK_PER_IMG = 16
    int y0 = (b & 15) * SPB;       // image-local scanline base
    int gs0 = img * HIMG + y0;     // global scanline index of own base

    __shared__ ull hbuf[HBUF][8];  // h-dilated words incl. halo
    __shared__ ull tbuf[SPB][8];
    __shared__ ull xbuf[SPB][8];

    int lane = threadIdx.x & 63;
    int wv = threadIdx.x >> 6;     // wave 0..3
    int ylo = (y0 - HALO < 0) ? 0 : y0 - HALO;
    int yhi = (y0 + SPB - 1 + HALO > HIMG - 1) ? HIMG - 1 : y0 + SPB - 1 + HALO;

    for (int yl = ylo + wv; yl <= yhi; yl += 4) {
        int gbase = (img * HIMG + yl) * W;
        bool own = (yl >= y0) && (yl < y0 + SPB);
        ull wt[8], wx[8], h[8];
#pragma unroll
        for (int k = 0; k < 8; ++k) wt[k] = __ballot(t[gbase + k * 64 + lane] > 0.0f);
        if (own) {
#pragma unroll
            for (int k = 0; k < 8; ++k) wx[k] = __ballot(x[gbase + k * 64 + lane] > 0.0f);
        }
#pragma unroll
        for (int k = 0; k < 8; ++k) {
            ull cur = wt[k];
            ull prev = k ? wt[k - 1]
                         : ((((cur >> 1) & 1ull) << 63) | (((cur >> 2) & 1ull) << 62) |
                            (((cur >> 3) & 1ull) << 61));
            ull next = (k < 7) ? wt[k + 1]
                               : (((cur >> 62) & 1ull) | (((cur >> 61) & 1ull) << 1) |
                                  (((cur >> 60) & 1ull) << 2));
            h[k] = hdil7(prev, cur, next);
        }
        int hy = yl - (y0 - HALO);
        int k = lane & 7;
        if (lane < 8) {
            hbuf[hy][k] = sel8(h, k);
        } else if (own && lane < 16) {
            tbuf[yl - y0][k] = sel8(wt, k);
            mT[(img * HIMG + yl) * 8 + k] = sel8(wt, k);
        } else if (own && lane < 24) {
            xbuf[yl - y0][k] = sel8(wx, k);
        }
    }
    __syncthreads();

    // phase 2: vertical dilation + per-word popcounts; thread = one own word
    int tid = threadIdx.x;
    int ys = tid >> 3;   // own scanline offset 0..31
    int c = tid & 7;
    int y = y0 + ys;
    ull wa = 0;
#pragma unroll
    for (int d = -3; d <= 3; ++d) {
        int yy = y + d;
        yy = yy < 0 ? -yy : (yy > HIMG - 1 ? 2 * (HIMG - 1) - yy : yy);
        wa |= hbuf[yy - (y0 - HALO)][c];
    }
    ull tw = tbuf[ys][c];
    ull fp = xbuf[ys][c] & ~wa;
    ull ng = ~wa;
    int gw = gs0 * 8 + tid;
    mFp[gw] = fp;
    mNeg[gw] = ng;
    int pT = __popcll(tw), pF = __popcll(fp), pN = __popcll(ng);
    // reduce within 32-thread groups (one tile = 4 scanlines = 32 words)
#pragma unroll
    for (int m = 1; m < 32; m <<= 1) {
        pT += __shfl_xor(pT, m, 64);
        pF += __shfl_xor(pF, m, 64);
        pN += __shfl_xor(pN, m, 64);
    }
    if ((lane & 31) == 0) {
        int tile = img * TILES_PER_ROW + (y0 >> 2) + (tid >> 5);
        cPos[tile] = pT; cFp[tile] = pF; cNeg[tile] = pN;
    }
}

// ------ K2: per-row scan of tile counts + magic divisors (tiny) ------
__global__ void scan_kernel(const int* __restrict__ cPos, const int* __restrict__ cFp,
                            const int* __restrict__ cNeg,
                            int* __restrict__ oPos, int* __restrict__ oCh,
                            int* __restrict__ rCp, int* __restrict__ rCc,
                            ull* __restrict__ rMp, ull* __restrict__ rMc,
                            int* __restrict__ rUseFp) {
    int r = blockIdx.x;
    int tid = threadIdx.x;  // blockDim == TILES_PER_ROW
    __shared__ int ssp[TILES_PER_ROW], ssf[TILES_PER_ROW], ssn[TILES_PER_ROW];
    int myp = cPos[r * TILES_PER_ROW + tid];
    int myf = cFp[r * TILES_PER_ROW + tid];
    int myn = cNeg[r * TILES_PER_ROW + tid];
    ssp[tid] = myp; ssf[tid] = myf; ssn[tid] = myn;
    __syncthreads();
    for (int off = 1; off < TILES_PER_ROW; off <<= 1) {
        int ap = 0, af = 0, an = 0;
        if (tid >= off) { ap = ssp[tid - off]; af = ssf[tid - off]; an = ssn[tid - off]; }
        __syncthreads();
        if (tid >= off) { ssp[tid] += ap; ssf[tid] += af; ssn[tid] += an; }
        __syncthreads();
    }
    int cp = ssp[TILES_PER_ROW - 1], cf = ssf[TILES_PER_ROW - 1], cn = ssn[TILES_PER_ROW - 1];
    bool useFp = cf > 0;
    int tile = r * TILES_PER_ROW + tid;
    oPos[tile] = ssp[tid] - myp;
    oCh[tile] = useFp ? (ssf[tid] - myf) : (ssn[tid] - myn);
    if (tid == 0) {
        int cc = useFp ? cf : cn;
        rCp[r] = cp; rCc[r] = cc; rUseFp[r] = useFp ? 1 : 0;
        ull dp_ = (ull)(cp > 0 ? cp : 1);
        ull dc_ = (ull)(cc > 0 ? cc : 1);
        rMp[r] = ((1ull << 40) + dp_ - 1) / dp_;  // exact floor(l/d) for l < 2^18
        rMc[r] = ((1ull << 40) + dc_ - 1) / dc_;
    }
}

// ------ K3: stable scatter-compaction with LDS-staged coalesced stores ------
__global__ __launch_bounds__(TPB)
void scatter_kernel(const float* __restrict__ x, const ull* __restrict__ mT,
                    const ull* __restrict__ mFp, const ull* __restrict__ mNeg,
                    const int* __restrict__ oPos, const int* __restrict__ oCh,
                    const int* __restrict__ rUseFp,
                    float* __restrict__ xp, float* __restrict__ xf) {
    int tile = blockIdx.x;
    int tid = threadIdx.x;
    int r = tile >> 7;
    bool useFp = rUseFp[r] != 0;
    int widx = tile * WORDS_PER_TILE + (tid >> 3);
    int shift = (tid & 7) * 8;
    unsigned bT = (unsigned)(mT[widx] >> shift) & 0xFF;
    ull chw = useFp ? mFp[widx] : mNeg[widx];
    unsigned bCh = (unsigned)(chw >> shift) & 0xFF;
    const float4* x4 = (const float4*)x;
    int b4 = tile * (TILE / 4) + tid * 2;
    float4 a = x4[b4], b = x4[b4 + 1];
    float xv[8] = {a.x, a.y, a.z, a.w, b.x, b.y, b.z, b.w};
    int p = __popc(bT), c = __popc(bCh);
    __shared__ int s[TPB];
    __shared__ float bufP[TILE], bufC[TILE];
    int v = p | (c << 16);
    s[tid] = v;
    __syncthreads();
    for (int off = 1; off < TPB; off <<= 1) {
        int add = tid >= off ? s[tid - off] : 0;
        __syncthreads();
        s[tid] += add;
        __syncthreads();
    }
    int excl = s[tid] - v;
    int ep = excl & 0xFFFF;
    int ec = excl >> 16;
#pragma unroll
    for (int e = 0; e < 8; ++e) {
        if ((bT >> e) & 1) bufP[ep++] = xv[e];
        if ((bCh >> e) & 1) bufC[ec++] = xv[e];
    }
    __syncthreads();
    int tot = s[TPB - 1];
    int P = tot & 0xFFFF, C = tot >> 16;
    int rL = r << LOG2L;
    int pbase = rL + oPos[tile];
    for (int i = tid; i < P; i += TPB) xp[pbase + i] = bufP[i];
    int cbase = rL + oCh[tile];
    for (int i = tid; i < C; i += TPB) xf[cbase + i] = bufC[i];
}

// ------ K4: loss; one contiguous row-aligned chunk per block ------
__global__ __launch_bounds__(TPB)
void loss_kernel(const float* __restrict__ x, const ull* __restrict__ mT,
                 const float* __restrict__ xp, const float* __restrict__ xf,
                 const int* __restrict__ rCp, const int* __restrict__ rCc,
                 const ull* __restrict__ rMp, const ull* __restrict__ rMc,
                 float* __restrict__ out, double inv_ntot) {
    int r = blockIdx.x >> 5;               // 32 blocks per row
    int cb = (blockIdx.x & 31) * CHUNK;    // chunk base (elements, within row)
    int rL = r << LOG2L;
    int cp = rCp[r], cc = rCc[r];          // wave-uniform scalars
    ull Mp = rMp[r], Mc = rMc[r];
    const float4* x4 = (const float4*)(x + rL + cb);
    const float* xpr = xp + rL;
    const float* xfr = xf + rL;
    const ull* mtr = mT + (rL >> 6);
    float local = 0.0f;
#pragma unroll
    for (int it = 0; it < LIT; ++it) {
        int o4 = it * TPB + threadIdx.x;
        unsigned l = (unsigned)(cb + (o4 << 2));
        float4 xv = x4[o4];
        unsigned tb = (unsigned)(mtr[l >> 6] >> (l & 63)) & 0xFu;
        float dps[4], dfs[4];
        if (cp > 0) {
            unsigned d = (unsigned)cp;
            unsigned q = (unsigned)(((ull)l * Mp) >> 40);
            unsigned m0 = l - q * d;
            unsigned m1 = m0 + 1; if (m1 == d) m1 = 0;
            unsigned m2 = m1 + 1; if (m2 == d) m2 = 0;
            unsigned m3 = m2 + 1; if (m3 == d) m3 = 0;
            dps[0] = xpr[m0]; dps[1] = xpr[m1]; dps[2] = xpr[m2]; dps[3] = xpr[m3];
        } else {
            dps[0] = dps[1] = dps[2] = dps[3] = 5.0f;
        }
        if (cc > 0) {
            unsigned d = (unsigned)cc;
            unsigned q = (unsigned)(((ull)l * Mc) >> 40);
            unsigned m0 = l - q * d;
            unsigned m1 = m0 + 1; if (m1 == d) m1 = 0;
            unsigned m2 = m1 + 1; if (m2 == d) m2 = 0;
            unsigned m3 = m2 + 1; if (m3 == d) m3 = 0;
            dfs[0] = xfr[m0]; dfs[1] = xfr[m1]; dfs[2] = xfr[m2]; dfs[3] = xfr[m3];
        } else {
            dfs[0] = dfs[1] = dfs[2] = dfs[3] = -5.0f;
        }
        float xs[4] = {xv.x, xv.y, xv.z, xv.w};
#pragma unroll
        for (int k = 0; k < 4; ++k) {
            float sim = dps[k] * xs[k];
            float e = softplus_f(sim) + softplus_f(-dps[k]) + 0.1f * softplus_f(dps[k] * dfs[k]);
            if ((tb >> k) & 1) e -= sim;
            local += e;
        }
    }
    __shared__ double sd[TPB];
    int tid = threadIdx.x;
    sd[tid] = (double)local;
    __syncthreads();
    for (int off = TPB / 2; off > 0; off >>= 1) {
        if (tid < off) sd[tid] += sd[tid + off];
        __syncthreads();
    }
    if (tid == 0) atomicAdd(out, (float)(sd[0] * inv_ntot));
}

extern "C" void kernel_launch(void* const* d_in, const int* in_sizes, int n_in,
                              void* d_out, int out_size, void* d_ws, size_t ws_size,
                              hipStream_t stream) {
    const float* x = (const float*)d_in[0];
    const float* t = (const float*)d_in[1];
    float* out = (float*)d_out;

    int ntot = in_sizes[0];          // 12,582,912
    int R = ntot >> LOG2L;           // 48
    int numTiles = ntot / TILE;      // 6144
    int nwords = ntot / 64;          // 196,608
    int nMaskBlk = ntot / (SPB * W); // 768

    char* ws = (char*)d_ws;
    size_t off = 0;
    auto alloc = [&](size_t bytes) {
        size_t p = off;
        off = (off + bytes + 255) & ~(size_t)255;
        return (void*)(ws + p);
    };
    ull* mT   = (ull*)alloc((size_t)nwords * 8);
    ull* mFp  = (ull*)alloc((size_t)nwords * 8);
    ull* mNeg = (ull*)alloc((size_t)nwords * 8);
    int* cPos = (int*)alloc(numTiles * sizeof(int));
    int* cFp  = (int*)alloc(numTiles * sizeof(int));
    int* cNeg = (int*)alloc(numTiles * sizeof(int));
    int* oPos = (int*)alloc(numTiles * sizeof(int));
    int* oCh  = (int*)alloc(numTiles * sizeof(int));
    int* rCp = (int*)alloc(R * sizeof(int));
    int* rCc = (int*)alloc(R * sizeof(int));
    int* rUseFp = (int*)alloc(R * sizeof(int));
    ull* rMp = (ull*)alloc(R * sizeof(ull));
    ull* rMc = (ull*)alloc(R * sizeof(ull));
    float* xp = (float*)alloc((size_t)ntot * sizeof(float));
    float* xf = (float*)alloc((size_t)ntot * sizeof(float));

    fused_mask_kernel<<<nMaskBlk, TPB, 0, stream>>>(x, t, mT, mFp, mNeg, cPos, cFp, cNeg, out);
    scan_kernel<<<R, TILES_PER_ROW, 0, stream>>>(cPos, cFp, cNeg, oPos, oCh,
                                                 rCp, rCc, rMp, rMc, rUseFp);
    scatter_kernel<<<numTiles, TPB, 0, stream>>>(x, mT, mFp, mNeg, oPos, oCh, rUseFp, xp, xf);
    loss_kernel<<<R * LBLK, TPB, 0, stream>>>(x, mT, xp, xf, rCp, rCc, rMp, rMc, out,
                                              1.0 / (double)ntot);
}